// Round 4
// baseline (3357.436 us; speedup 1.0000x reference)
//
#include <hip/hip_runtime.h>
#include <hip/hip_bf16.h>

// Problem constants (fixed by the reference)
// B=1024, L=128, W=512, S=8, STEPS=12, VOCAB=32, NLAB=10

typedef unsigned short u16;
typedef __attribute__((ext_vector_type(8))) short short8;   // 8 x bf16 (4 VGPRs)
typedef __attribute__((ext_vector_type(4))) float f32x4;

__device__ __forceinline__ float bf2f(u16 v) {
    union { unsigned int u; float f; } x; x.u = ((unsigned int)v) << 16; return x.f;
}
__device__ __forceinline__ u16 f2bf(float f) {
    union { float f; unsigned int u; } x; x.f = f;
    unsigned int u = x.u;
    return (u16)((u + 0x7FFFu + ((u >> 16) & 1u)) >> 16);   // RNE
}
__device__ __forceinline__ float sigmoidf_(float v) { return 1.f / (1.f + expf(-v)); }

// ---------------------------------------------------------------------------
// Input-dtype detection: true-bf16 buffers have ~100% "plausible" u16s;
// f32 buffers read as u16 have ~50% (low mantissa halves are random bits).
// Scans embed u16s [1024,1536): nonzero data under BOTH interpretations.
// flag=1 -> inputs are bf16; flag=0 -> inputs are f32.
// ---------------------------------------------------------------------------
__device__ __forceinline__ int sane16(u16 u) {
    if ((u & 0x7FFF) == 0) return 1;
    int e = (u >> 7) & 0xFF;
    return (e >= 0x33 && e <= 0x43) ? 1 : 0;    // |v| in ~[2^-12, 2^4]
}
__global__ __launch_bounds__(256) void detect_k(const u16* __restrict__ raw,
                                                int* __restrict__ flag) {
    const int t = threadIdx.x;
    int c = sane16(raw[1024 + t * 2]) + sane16(raw[1024 + t * 2 + 1]);
#pragma unroll
    for (int off = 32; off; off >>= 1) c += __shfl_down(c, off, 64);
    __shared__ int red[4];
    if ((t & 63) == 0) red[t >> 6] = c;
    __syncthreads();
    if (t == 0) *flag = (red[0] + red[1] + red[2] + red[3] >= 448) ? 1 : 0;
}

// ---------------------------------------------------------------------------
// Canonicalize all float tensors to bf16 (copy if already bf16, cvt if f32).
// ---------------------------------------------------------------------------
struct CT { const void* src[20]; int n[20]; int off[20]; };
__global__ __launch_bounds__(256) void conv_k(CT ct, u16* __restrict__ dstBase,
                                              const int* __restrict__ flag) {
    const int isbf = *flag;
    const int gid = blockIdx.x * 256 + threadIdx.x;
    const int stride = gridDim.x * 256;
    for (int tnum = 0; tnum < 20; ++tnum) {
        const int n = ct.n[tnum];
        u16* dst = dstBase + ct.off[tnum];
        if (isbf) {
            const u16* s = (const u16*)ct.src[tnum];
            for (int i = gid; i < n; i += stride) dst[i] = s[i];
        } else {
            const float* s = (const float*)ct.src[tnum];
            for (int i = gid; i < n; i += stride) dst[i] = f2bf(s[i]);
        }
    }
}

// ---------------------------------------------------------------------------
// Generic batched GEMM: C[z][m][n] = epi( sum_k A[z][m][k] * Bw[z][n][k] )
// A bf16 [M,K] (lda stride, per-z offset table), Bw bf16 [N,K] K-contiguous.
// 128x128 tile, BK=64, 4 waves, mfma_f32_16x16x32_bf16, XOR-swizzled LDS.
// ---------------------------------------------------------------------------
struct GP {
    const u16* A; long lda; long aOff[8];
    const u16* Bw; long bOff; int K;
    const u16* bias; long biasOff;
    const u16* add; long ldadd; long addOff;   // EPI 1
    const float* gate;                          // EPI 3: gate[m*8+z]
    void* C; long ldc; long cOff;
    float* C2;                                  // EPI 4: h (f32); EPI 5: hn (f32)
};

template<int EPI>
__global__ __launch_bounds__(256, 2) void gemm_k(GP p) {
    __shared__ __align__(16) u16 lA[128 * 64];
    __shared__ __align__(16) u16 lB[128 * 64];
    const int t    = threadIdx.x;
    const int lane = t & 63;
    const int wv   = t >> 6;
    const int z    = blockIdx.z;
    const int m0   = blockIdx.x * 128;
    const int n0   = blockIdx.y * 128;

    const u16* Ab = p.A + p.aOff[z] + (long)m0 * p.lda;
    const u16* Bb = p.Bw + (long)z * p.bOff + (long)n0 * p.K;

    f32x4 acc[4][4];
#pragma unroll
    for (int i = 0; i < 4; i++)
#pragma unroll
        for (int j = 0; j < 4; j++) acc[i][j] = (f32x4){0.f, 0.f, 0.f, 0.f};

    const int wm   = (wv & 1) * 64;
    const int wn   = (wv >> 1) * 64;
    const int fr   = lane & 15;
    const int quad = lane >> 4;

    // Staging: LDS[row][c8] = Global[row][c8 ^ (row&7)]  (XOR bank swizzle)
    int rowA[4], src8A[4];
#pragma unroll
    for (int it = 0; it < 4; ++it) {
        int flat = it * 256 + t;
        rowA[it] = flat >> 3;
        src8A[it] = (flat & 7) ^ (rowA[it] & 7);
    }

    const int nk = p.K >> 6;
    for (int kt = 0; kt < nk; ++kt) {
        const long kbase = (long)kt * 64;
        short8 ra[4], rb[4];
#pragma unroll
        for (int it = 0; it < 4; ++it)
            ra[it] = *(const short8*)(Ab + (long)rowA[it] * p.lda + kbase + src8A[it] * 8);
#pragma unroll
        for (int it = 0; it < 4; ++it)
            rb[it] = *(const short8*)(Bb + (long)rowA[it] * p.K + kbase + src8A[it] * 8);
#pragma unroll
        for (int it = 0; it < 4; ++it) {
            int flat = it * 256 + t;
            *(short8*)&lA[flat * 8] = ra[it];
            *(short8*)&lB[flat * 8] = rb[it];
        }
        __syncthreads();
#pragma unroll
        for (int kk = 0; kk < 2; ++kk) {
            const int q = kk * 4 + quad;                  // k-block 0..7 within BK=64
            short8 aF[4], bF[4];
#pragma unroll
            for (int mi = 0; mi < 4; mi++) {
                int row = wm + mi * 16 + fr;
                aF[mi] = *(const short8*)&lA[row * 64 + (q ^ (row & 7)) * 8];
            }
#pragma unroll
            for (int ni = 0; ni < 4; ni++) {
                int row = wn + ni * 16 + fr;
                bF[ni] = *(const short8*)&lB[row * 64 + (q ^ (row & 7)) * 8];
            }
#pragma unroll
            for (int mi = 0; mi < 4; mi++)
#pragma unroll
                for (int ni = 0; ni < 4; ni++)
                    acc[mi][ni] = __builtin_amdgcn_mfma_f32_16x16x32_bf16(
                        aF[mi], bF[ni], acc[mi][ni], 0, 0, 0);
        }
        __syncthreads();
    }

    // Epilogue: D row = quad*4+reg, col = lane&15  (verified C/D layout)
#pragma unroll
    for (int mi = 0; mi < 4; mi++) {
#pragma unroll
        for (int ni = 0; ni < 4; ni++) {
            const int mg = m0 + wm + mi * 16 + quad * 4;
            const int ng = n0 + wn + ni * 16 + fr;
#pragma unroll
            for (int r = 0; r < 4; r++) {
                float v = acc[mi][ni][r];
                const long row = mg + r;
                if (EPI == 0) {                       // tanh(acc+bias) -> bf16
                    v = tanhf(v + bf2f(p.bias[(long)z * p.biasOff + ng]));
                    ((u16*)p.C)[(long)z * p.cOff + row * p.ldc + ng] = f2bf(v);
                } else if (EPI == 1) {                // tanh(acc+add+bias) -> bf16
                    float ad = bf2f(p.add[(long)z * p.addOff + row * p.ldadd + ng]);
                    v = tanhf(v + ad + bf2f(p.bias[(long)z * p.biasOff + ng]));
                    ((u16*)p.C)[(long)z * p.cOff + row * p.ldc + ng] = f2bf(v);
                } else if (EPI == 2) {                // acc+bias -> f32 (gi)
                    v = v + bf2f(p.bias[(long)z * p.biasOff + ng]);
                    ((float*)p.C)[(long)z * p.cOff + row * p.ldc + ng] = v;
                } else if (EPI == 5) {                // gh fused: r/z add into gi, n -> hn
                    v = v + bf2f(p.bias[(long)z * p.biasOff + ng]);
                    if (ng < 1024) {
                        ((float*)p.C)[(long)z * p.cOff + row * p.ldc + ng] += v;
                    } else {
                        p.C2[row * 4096 + (long)z * 512 + (ng - 1024)] = v;
                    }
                } else if (EPI == 3) {                // gate*tanh(acc+bias) -> f32
                    v = tanhf(v + bf2f(p.bias[(long)z * p.biasOff + ng]));
                    v *= p.gate[row * 8 + z];
                    ((float*)p.C)[(long)z * p.cOff + row * p.ldc + ng] = v;
                } else {                              // EPI 4: encode mix -> summary
                    v = tanhf(v + bf2f(p.bias[ng]));
                    u16 b = f2bf(v);
                    ((u16*)p.C)[row * 1024 + ng] = b;         // shared[:, 0:512] = h0
                    ((u16*)p.C)[row * 1024 + 512 + ng] = b;   // shared[:, 512:1024] = summary
                    p.C2[row * 512 + ng] = v;                 // h f32
                }
            }
        }
    }
}

// ---------------------------------------------------------------------------
// Encode: masked mean / masked max / token-at-position-(count-1) -> cat [B,1536]
// ---------------------------------------------------------------------------
__global__ __launch_bounds__(256) void encode_k(const int* __restrict__ x,
                                                const u16* __restrict__ embed,
                                                u16* __restrict__ cat) {
    __shared__ int toks[128];
    __shared__ int cnt_s;
    const int b = blockIdx.x, t = threadIdx.x;
    if (t < 128) toks[t] = x[b * 128 + t];
    __syncthreads();
    if (t == 0) {
        int c = 0;
        for (int l = 0; l < 128; l++) c += (toks[l] != 0);
        cnt_s = c;
    }
    __syncthreads();
    const int cnt = cnt_s;
    const int lastTok = toks[cnt > 0 ? cnt - 1 : 0];
    for (int w = t; w < 512; w += 256) {
        float sum = 0.f, mx = -10000.f;
        for (int l = 0; l < 128; l++) {
            int tok = toks[l];                 // uniform across block: no divergence
            if (tok != 0) {
                float e = bf2f(embed[tok * 512 + w]);
                sum += e;
                mx = fmaxf(mx, e);
            }
        }
        float mean = sum / (float)(cnt > 0 ? cnt : 1);
        float last = bf2f(embed[lastTok * 512 + w]);
        cat[(long)b * 1536 + w]        = f2bf(mean);
        cat[(long)b * 1536 + 512 + w]  = f2bf(mx);
        cat[(long)b * 1536 + 1024 + w] = f2bf(last);
    }
}

// ---------------------------------------------------------------------------
// Fused GRU + gate-dot + prismion.  One block per (b,s), 128 threads x 4 elems.
// gi holds [ir+hr, iz+hz, inn] (r/z pre-summed by EPI5); hn separate.
// ---------------------------------------------------------------------------
__global__ __launch_bounds__(128) void gru_k(const float* __restrict__ gi,
                                             const float* __restrict__ hn_buf,
                                             float* __restrict__ hs,
                                             u16* __restrict__ hs_b,
                                             u16* __restrict__ prism,
                                             float* __restrict__ gate,
                                             const u16* __restrict__ Wg,
                                             const u16* __restrict__ bg,
                                             const u16* __restrict__ phase,
                                             const u16* __restrict__ pgain) {
    const int bs = blockIdx.x;
    const int b = bs >> 3, s = bs & 7;
    const int t = threadIdx.x;
    const int w = t * 4;
    const long gbase = (long)b * 12288 + s * 1536;
    const long hbase = (long)b * 4096 + s * 512;

    f32x4 rz_r = *(const f32x4*)(gi + gbase + w);            // ir+hr
    f32x4 rz_z = *(const f32x4*)(gi + gbase + 512 + w);      // iz+hz
    f32x4 in_  = *(const f32x4*)(gi + gbase + 1024 + w);     // inn
    f32x4 hn   = *(const f32x4*)(hn_buf + hbase + w);        // hn
    f32x4 h    = *(const f32x4*)(hs + hbase + w);

    float gpart = 0.f;
    f32x4 hnew;
    u16 hb[4], pb[4];
#pragma unroll
    for (int i = 0; i < 4; i++) {
        float r  = sigmoidf_(rz_r[i]);
        float zz = sigmoidf_(rz_z[i]);
        float n  = tanhf(in_[i] + r * hn[i]);
        float hv = (1.f - zz) * n + zz * h[i];
        hnew[i] = hv;
        hb[i] = f2bf(hv);
        gpart += bf2f(Wg[s * 512 + w + i]) * hv;
        float ph = bf2f(phase[s * 512 + w + i]);
        float pg = bf2f(pgain[s * 512 + w + i]);
        float gain = (pg > 20.f) ? pg : log1pf(expf(pg));   // softplus
        float c = cosf(hv + ph);
        pb[i] = f2bf(c * c * gain);
    }
    *(f32x4*)(hs + hbase + w) = hnew;
    *(ushort4*)(hs_b + hbase + w)  = make_ushort4(hb[0], hb[1], hb[2], hb[3]);
    *(ushort4*)(prism + hbase + w) = make_ushort4(pb[0], pb[1], pb[2], pb[3]);

    // block-reduce gate dot (512 elems)
#pragma unroll
    for (int off = 32; off; off >>= 1) gpart += __shfl_down(gpart, off, 64);
    __shared__ float red[2];
    if ((t & 63) == 0) red[t >> 6] = gpart;
    __syncthreads();
    if (t == 0) gate[bs] = sigmoidf_(red[0] + red[1] + bf2f(bg[s]));
}

// ---------------------------------------------------------------------------
// delta = sum_s upd / sqrt(S);  h = tanh(h*decay + delta); shared[:,0:512] = h
// ---------------------------------------------------------------------------
__global__ __launch_bounds__(256) void hupd_k(const float* __restrict__ upd,
                                              float* __restrict__ h,
                                              u16* __restrict__ shared_b,
                                              const u16* __restrict__ decay_p) {
    const int idx = blockIdx.x * 256 + threadIdx.x;   // over B*W
    const int b = idx >> 9, w = idx & 511;
    const long base = (long)b * 4096 + w;
    float dsum = 0.f;
#pragma unroll
    for (int s = 0; s < 8; s++) dsum += upd[base + s * 512];
    const float decay = sigmoidf_(bf2f(decay_p[0]));
    const float hv = tanhf(h[idx] * decay + dsum * 0.35355339059327373f);
    h[idx] = hv;
    shared_b[(long)b * 1024 + w] = f2bf(hv);
}

// ---------------------------------------------------------------------------
// Final head: out[b,j] = h[b,:] . W_out[j,:] + b_out[j]   (one wave per b)
// Output dtype follows detected input dtype (bf16 vs f32).
// ---------------------------------------------------------------------------
__global__ __launch_bounds__(64) void out_k(const float* __restrict__ h,
                                            const u16* __restrict__ Wout,
                                            const u16* __restrict__ bout,
                                            void* __restrict__ out,
                                            const int* __restrict__ flag) {
    const int b = blockIdx.x, lane = threadIdx.x;
    const int isbf = *flag;
    for (int j = 0; j < 10; j++) {
        float p = 0.f;
#pragma unroll
        for (int k = 0; k < 8; k++) {
            int w = lane + k * 64;
            p += h[(long)b * 512 + w] * bf2f(Wout[j * 512 + w]);
        }
#pragma unroll
        for (int off = 32; off; off >>= 1) p += __shfl_down(p, off, 64);
        if (lane == 0) {
            float val = p + bf2f(bout[j]);
            if (isbf) ((u16*)out)[b * 10 + j] = f2bf(val);
            else      ((float*)out)[b * 10 + j] = val;
        }
    }
}

// ---------------------------------------------------------------------------
extern "C" void kernel_launch(void* const* d_in, const int* in_sizes, int n_in,
                              void* d_out, int out_size, void* d_ws, size_t ws_size,
                              hipStream_t stream) {
    (void)n_in; (void)out_size; (void)ws_size;
    const int* x = (const int*)d_in[0];

    char* pp = (char*)d_ws;
    auto carve = [&](size_t n) { char* r = pp; pp += (n + 255) & ~(size_t)255; return (void*)r; };

    // --- canonical bf16 parameter block (~44 MB) ---
    CT ct;
    size_t ctot = 0;
    for (int i = 0; i < 20; i++) {
        ct.src[i] = d_in[i + 1];
        ct.n[i]   = in_sizes[i + 1];
        ct.off[i] = (int)ctot;
        ctot += ((size_t)in_sizes[i + 1] + 15) & ~(size_t)15;   // 16-elem align
    }
    u16* canon = (u16*)carve(ctot * 2);
    const u16* embed  = canon + ct.off[0];
    const u16* W_mix  = canon + ct.off[1];
    const u16* b_mix  = canon + ct.off[2];
    const u16* W_in   = canon + ct.off[3];
    const u16* b_in   = canon + ct.off[4];
    const u16* W_link = canon + ct.off[5];
    const u16* b_link = canon + ct.off[6];
    const u16* W_ih   = canon + ct.off[7];
    const u16* b_ih   = canon + ct.off[8];
    const u16* W_hh   = canon + ct.off[9];
    const u16* b_hh   = canon + ct.off[10];
    const u16* W_gate = canon + ct.off[11];
    const u16* b_gate = canon + ct.off[12];
    const u16* phase  = canon + ct.off[13];
    const u16* pgain  = canon + ct.off[14];
    const u16* W_delta= canon + ct.off[15];
    const u16* b_delta= canon + ct.off[16];
    const u16* decayp = canon + ct.off[17];
    const u16* W_out  = canon + ct.off[18];
    const u16* b_out  = canon + ct.off[19];

    // --- activations (~119 MB) ---
    int*   flag     = (int*)  carve(256);
    u16*   cat      = (u16*)  carve((size_t)1024 * 1536 * 2);   //  3 MB
    u16*   shared_b = (u16*)  carve((size_t)1024 * 1024 * 2);   //  2 MB
    float* h        = (float*)carve((size_t)1024 * 512 * 4);    //  2 MB
    u16*   f0       = (u16*)  carve((size_t)1024 * 4096 * 2);   //  8 MB
    u16*   feats    = (u16*)  carve((size_t)1024 * 4096 * 2);   //  8 MB
    float* hs       = (float*)carve((size_t)1024 * 4096 * 4);   // 16 MB
    u16*   hs_b     = (u16*)  carve((size_t)1024 * 4096 * 2);   //  8 MB
    float* gi       = (float*)carve((size_t)1024 * 12288 * 4);  // 48 MB
    float* hn       = (float*)carve((size_t)1024 * 4096 * 4);   // 16 MB (upd aliases)
    u16*   prism    = (u16*)  carve((size_t)1024 * 4096 * 2);   //  8 MB
    float* gate     = (float*)carve((size_t)1024 * 8 * 4);      // 32 KB
    float* upd      = hn;  // dead after gru_k reads hn

    (void)hipMemsetAsync(hs,   0, (size_t)1024 * 4096 * 4, stream);
    (void)hipMemsetAsync(hs_b, 0, (size_t)1024 * 4096 * 2, stream);

    detect_k<<<dim3(1), dim3(256), 0, stream>>>((const u16*)d_in[1], flag);
    conv_k<<<dim3(1024), dim3(256), 0, stream>>>(ct, canon, flag);

    encode_k<<<dim3(1024), dim3(256), 0, stream>>>(x, embed, cat);

    {   // summary = tanh(cat @ W_mix^T + b_mix) ; h0 = summary; shared = [h0, summary]
        GP p{}; p.A = cat; p.lda = 1536; p.Bw = W_mix; p.bOff = 0; p.K = 1536;
        p.bias = b_mix; p.biasOff = 0; p.C = shared_b; p.ldc = 1024; p.cOff = 0; p.C2 = h;
        gemm_k<4><<<dim3(8, 4, 1), dim3(256), 0, stream>>>(p);
    }

    for (int step = 0; step < 12; ++step) {
        {   // f0 = tanh(shared @ W_in^T + b_in)   [B, S*W]
            GP p{}; p.A = shared_b; p.lda = 1024; p.Bw = W_in; p.bOff = 0; p.K = 1024;
            p.bias = b_in; p.biasOff = 0; p.C = f0; p.ldc = 4096; p.cOff = 0;
            gemm_k<0><<<dim3(8, 32, 1), dim3(256), 0, stream>>>(p);
        }
        {   // feats = tanh(f0 + prev @ W_link^T + b_link), prev = pocket (s-1)%8
            GP p{}; p.A = f0; p.lda = 4096;
            for (int s = 0; s < 8; s++) p.aOff[s] = (long)((s + 7) & 7) * 512;
            p.Bw = W_link; p.bOff = (long)512 * 512; p.K = 512;
            p.bias = b_link; p.biasOff = 512;
            p.add = f0; p.ldadd = 4096; p.addOff = 512;
            p.C = feats; p.ldc = 4096; p.cOff = 512;
            gemm_k<1><<<dim3(8, 4, 8), dim3(256), 0, stream>>>(p);
        }
        {   // gi = feats @ W_ih^T + b_ih
            GP p{}; p.A = feats; p.lda = 4096;
            for (int s = 0; s < 8; s++) p.aOff[s] = (long)s * 512;
            p.Bw = W_ih; p.bOff = (long)1536 * 512; p.K = 512;
            p.bias = b_ih; p.biasOff = 1536;
            p.C = gi; p.ldc = 12288; p.cOff = 1536;
            gemm_k<2><<<dim3(8, 12, 8), dim3(256), 0, stream>>>(p);
        }
        {   // gh = hs @ W_hh^T + b_hh ; r/z parts += into gi, n part -> hn
            GP p{}; p.A = hs_b; p.lda = 4096;
            for (int s = 0; s < 8; s++) p.aOff[s] = (long)s * 512;
            p.Bw = W_hh; p.bOff = (long)1536 * 512; p.K = 512;
            p.bias = b_hh; p.biasOff = 1536;
            p.C = gi; p.ldc = 12288; p.cOff = 1536; p.C2 = hn;
            gemm_k<5><<<dim3(8, 12, 8), dim3(256), 0, stream>>>(p);
        }
        gru_k<<<dim3(8192), dim3(128), 0, stream>>>(gi, hn, hs, hs_b, prism, gate,
                                                    W_gate, b_gate, phase, pgain);
        {   // upd = gate * tanh(prism @ W_delta^T + b_delta)   (upd aliases hn)
            GP p{}; p.A = prism; p.lda = 4096;
            for (int s = 0; s < 8; s++) p.aOff[s] = (long)s * 512;
            p.Bw = W_delta; p.bOff = (long)512 * 512; p.K = 512;
            p.bias = b_delta; p.biasOff = 512; p.gate = gate;
            p.C = upd; p.ldc = 4096; p.cOff = 512;
            gemm_k<3><<<dim3(8, 4, 8), dim3(256), 0, stream>>>(p);
        }
        hupd_k<<<dim3(2048), dim3(256), 0, stream>>>(upd, h, shared_b, decayp);
    }

    out_k<<<dim3(1024), dim3(64), 0, stream>>>(h, W_out, b_out, d_out, flag);
}

// Round 5
// 2612.537 us; speedup vs baseline: 1.2851x; 1.2851x over previous
//
#include <hip/hip_runtime.h>
#include <hip/hip_bf16.h>

// Problem constants (fixed by the reference)
// B=1024, L=128, W=512, S=8, STEPS=12, VOCAB=32, NLAB=10

typedef unsigned short u16;
typedef __attribute__((ext_vector_type(8))) short short8;   // 8 x bf16 (4 VGPRs)
typedef __attribute__((ext_vector_type(4))) float f32x4;

__device__ __forceinline__ float bf2f(u16 v) {
    union { unsigned int u; float f; } x; x.u = ((unsigned int)v) << 16; return x.f;
}
__device__ __forceinline__ u16 f2bf(float f) {
    union { float f; unsigned int u; } x; x.f = f;
    unsigned int u = x.u;
    return (u16)((u + 0x7FFFu + ((u >> 16) & 1u)) >> 16);   // RNE
}
__device__ __forceinline__ float sigmoidf_(float v) { return 1.f / (1.f + expf(-v)); }

// Async global->LDS, 16B per lane. LDS dest must be wave-uniform base + lane*16
// (our flat = it*256 + wv*64 + lane satisfies this). C-style casts = addrspacecast.
__device__ __forceinline__ void gload_lds16(const u16* g, u16* l) {
    __builtin_amdgcn_global_load_lds(
        (const __attribute__((address_space(1))) unsigned int*)g,
        (__attribute__((address_space(3))) unsigned int*)l, 16, 0, 0);
}

// ---------------------------------------------------------------------------
// Input-dtype detection: true-bf16 buffers have ~100% "plausible" u16s;
// f32 buffers read as u16 have ~50% (low mantissa halves are random bits).
// ---------------------------------------------------------------------------
__device__ __forceinline__ int sane16(u16 u) {
    if ((u & 0x7FFF) == 0) return 1;
    int e = (u >> 7) & 0xFF;
    return (e >= 0x33 && e <= 0x43) ? 1 : 0;    // |v| in ~[2^-12, 2^4]
}
__global__ __launch_bounds__(256) void detect_k(const u16* __restrict__ raw,
                                                int* __restrict__ flag) {
    const int t = threadIdx.x;
    int c = sane16(raw[1024 + t * 2]) + sane16(raw[1024 + t * 2 + 1]);
#pragma unroll
    for (int off = 32; off; off >>= 1) c += __shfl_down(c, off, 64);
    __shared__ int red[4];
    if ((t & 63) == 0) red[t >> 6] = c;
    __syncthreads();
    if (t == 0) *flag = (red[0] + red[1] + red[2] + red[3] >= 448) ? 1 : 0;
}

// ---------------------------------------------------------------------------
// Canonicalize all float tensors to bf16 (copy if already bf16, cvt if f32).
// ---------------------------------------------------------------------------
struct CT { const void* src[20]; int n[20]; int off[20]; };
__global__ __launch_bounds__(256) void conv_k(CT ct, u16* __restrict__ dstBase,
                                              const int* __restrict__ flag) {
    const int isbf = *flag;
    const int gid = blockIdx.x * 256 + threadIdx.x;
    const int stride = gridDim.x * 256;
    for (int tnum = 0; tnum < 20; ++tnum) {
        const int n = ct.n[tnum];
        u16* dst = dstBase + ct.off[tnum];
        if (isbf) {
            const u16* s = (const u16*)ct.src[tnum];
            for (int i = gid; i < n; i += stride) dst[i] = s[i];
        } else {
            const float* s = (const float*)ct.src[tnum];
            for (int i = gid; i < n; i += stride) dst[i] = f2bf(s[i]);
        }
    }
}

// ---------------------------------------------------------------------------
// Generic batched GEMM: C[z][m][n] = epi( sum_k A[z][m][k] * Bw[z][n][k] )
// A bf16 [M,K] (lda stride, per-z offset table), Bw bf16 [N,K] K-contiguous.
// 128x128 tile, BK=64, 4 waves, mfma_f32_16x16x32_bf16, XOR-swizzled LDS,
// global_load_lds(16B) staging (m97 structure).
// ---------------------------------------------------------------------------
struct GP {
    const u16* A; long lda; long aOff[8];
    const u16* Bw; long bOff; int K;
    const u16* bias; long biasOff;
    const u16* add; long ldadd; long addOff;   // EPI 1
    const float* gate;                          // EPI 3: gate[m*8+z]
    void* C; long ldc; long cOff;
    float* C2;                                  // EPI 4: h (f32); EPI 5: hn (f32)
};

template<int EPI>
__global__ __launch_bounds__(256) void gemm_k(GP p) {
    __shared__ __align__(16) u16 lA[128 * 64];
    __shared__ __align__(16) u16 lB[128 * 64];
    const int t    = threadIdx.x;
    const int lane = t & 63;
    const int wv   = t >> 6;
    const int z    = blockIdx.z;
    const int m0   = blockIdx.x * 128;
    const int n0   = blockIdx.y * 128;

    const u16* Ab = p.A + p.aOff[z] + (long)m0 * p.lda;
    const u16* Bb = p.Bw + (long)z * p.bOff + (long)n0 * p.K;

    f32x4 acc[4][4];
#pragma unroll
    for (int i = 0; i < 4; i++)
#pragma unroll
        for (int j = 0; j < 4; j++) acc[i][j] = (f32x4){0.f, 0.f, 0.f, 0.f};

    const int wm   = (wv & 1) * 64;
    const int wn   = (wv >> 1) * 64;
    const int fr   = lane & 15;
    const int quad = lane >> 4;

    // Staging map: LDS[row][c8] = Global[row][c8 ^ (row&7)]  (XOR bank swizzle)
    // flat = it*256 + t; row = flat>>3; c8 = flat&7.
    int rowA[4], src8A[4];
#pragma unroll
    for (int it = 0; it < 4; ++it) {
        int flat = it * 256 + t;
        rowA[it] = flat >> 3;
        src8A[it] = (flat & 7) ^ (rowA[it] & 7);
    }

    const int nk = p.K >> 6;
    for (int kt = 0; kt < nk; ++kt) {
        const long kbase = (long)kt * 64;
#pragma unroll
        for (int it = 0; it < 4; ++it)
            gload_lds16(Ab + (long)rowA[it] * p.lda + kbase + src8A[it] * 8,
                        lA + (it * 256 + t) * 8);
#pragma unroll
        for (int it = 0; it < 4; ++it)
            gload_lds16(Bb + (long)rowA[it] * p.K + kbase + src8A[it] * 8,
                        lB + (it * 256 + t) * 8);
        __syncthreads();                                  // drains vmcnt
#pragma unroll
        for (int kk = 0; kk < 2; ++kk) {
            const int q = kk * 4 + quad;                  // k-block 0..7 within BK=64
            short8 aF[4], bF[4];
#pragma unroll
            for (int mi = 0; mi < 4; mi++) {
                int row = wm + mi * 16 + fr;
                aF[mi] = *(const short8*)&lA[row * 64 + (q ^ (row & 7)) * 8];
            }
#pragma unroll
            for (int ni = 0; ni < 4; ni++) {
                int row = wn + ni * 16 + fr;
                bF[ni] = *(const short8*)&lB[row * 64 + (q ^ (row & 7)) * 8];
            }
#pragma unroll
            for (int mi = 0; mi < 4; mi++)
#pragma unroll
                for (int ni = 0; ni < 4; ni++)
                    acc[mi][ni] = __builtin_amdgcn_mfma_f32_16x16x32_bf16(
                        aF[mi], bF[ni], acc[mi][ni], 0, 0, 0);
        }
        __syncthreads();
    }

    // Epilogue: D row = quad*4+reg, col = lane&15  (verified C/D layout)
#pragma unroll
    for (int mi = 0; mi < 4; mi++) {
#pragma unroll
        for (int ni = 0; ni < 4; ni++) {
            const int mg = m0 + wm + mi * 16 + quad * 4;
            const int ng = n0 + wn + ni * 16 + fr;
#pragma unroll
            for (int r = 0; r < 4; r++) {
                float v = acc[mi][ni][r];
                const long row = mg + r;
                if (EPI == 0) {                       // tanh(acc+bias) -> bf16
                    v = tanhf(v + bf2f(p.bias[(long)z * p.biasOff + ng]));
                    ((u16*)p.C)[(long)z * p.cOff + row * p.ldc + ng] = f2bf(v);
                } else if (EPI == 1) {                // tanh(acc+add+bias) -> bf16
                    float ad = bf2f(p.add[(long)z * p.addOff + row * p.ldadd + ng]);
                    v = tanhf(v + ad + bf2f(p.bias[(long)z * p.biasOff + ng]));
                    ((u16*)p.C)[(long)z * p.cOff + row * p.ldc + ng] = f2bf(v);
                } else if (EPI == 2) {                // acc+bias -> f32 (gi)
                    v = v + bf2f(p.bias[(long)z * p.biasOff + ng]);
                    ((float*)p.C)[(long)z * p.cOff + row * p.ldc + ng] = v;
                } else if (EPI == 5) {                // gh fused: r/z add into gi, n -> hn
                    v = v + bf2f(p.bias[(long)z * p.biasOff + ng]);
                    if (ng < 1024) {
                        ((float*)p.C)[(long)z * p.cOff + row * p.ldc + ng] += v;
                    } else {
                        p.C2[row * 4096 + (long)z * 512 + (ng - 1024)] = v;
                    }
                } else if (EPI == 3) {                // gate*tanh(acc+bias) -> f32
                    v = tanhf(v + bf2f(p.bias[(long)z * p.biasOff + ng]));
                    v *= p.gate[row * 8 + z];
                    ((float*)p.C)[(long)z * p.cOff + row * p.ldc + ng] = v;
                } else {                              // EPI 4: encode mix -> summary
                    v = tanhf(v + bf2f(p.bias[ng]));
                    u16 b = f2bf(v);
                    ((u16*)p.C)[row * 1024 + ng] = b;         // shared[:, 0:512] = h0
                    ((u16*)p.C)[row * 1024 + 512 + ng] = b;   // shared[:, 512:1024] = summary
                    p.C2[row * 512 + ng] = v;                 // h f32
                }
            }
        }
    }
}

// ---------------------------------------------------------------------------
// Encode: masked mean / masked max / token-at-position-(count-1) -> cat [B,1536]
// ---------------------------------------------------------------------------
__global__ __launch_bounds__(256) void encode_k(const int* __restrict__ x,
                                                const u16* __restrict__ embed,
                                                u16* __restrict__ cat) {
    __shared__ int toks[128];
    __shared__ int cnt_s;
    const int b = blockIdx.x, t = threadIdx.x;
    if (t < 128) toks[t] = x[b * 128 + t];
    __syncthreads();
    if (t == 0) {
        int c = 0;
        for (int l = 0; l < 128; l++) c += (toks[l] != 0);
        cnt_s = c;
    }
    __syncthreads();
    const int cnt = cnt_s;
    const int lastTok = toks[cnt > 0 ? cnt - 1 : 0];
    for (int w = t; w < 512; w += 256) {
        float sum = 0.f, mx = -10000.f;
        for (int l = 0; l < 128; l++) {
            int tok = toks[l];                 // uniform across block: no divergence
            if (tok != 0) {
                float e = bf2f(embed[tok * 512 + w]);
                sum += e;
                mx = fmaxf(mx, e);
            }
        }
        float mean = sum / (float)(cnt > 0 ? cnt : 1);
        float last = bf2f(embed[lastTok * 512 + w]);
        cat[(long)b * 1536 + w]        = f2bf(mean);
        cat[(long)b * 1536 + 512 + w]  = f2bf(mx);
        cat[(long)b * 1536 + 1024 + w] = f2bf(last);
    }
}

// ---------------------------------------------------------------------------
// Fused GRU + gate-dot + prismion.  One block per (b,s), 128 threads x 4 elems.
// gi holds [ir+hr, iz+hz, inn] (r/z pre-summed by EPI5); hn separate.
// ---------------------------------------------------------------------------
__global__ __launch_bounds__(128) void gru_k(const float* __restrict__ gi,
                                             const float* __restrict__ hn_buf,
                                             float* __restrict__ hs,
                                             u16* __restrict__ hs_b,
                                             u16* __restrict__ prism,
                                             float* __restrict__ gate,
                                             const u16* __restrict__ Wg,
                                             const u16* __restrict__ bg,
                                             const u16* __restrict__ phase,
                                             const u16* __restrict__ pgain) {
    const int bs = blockIdx.x;
    const int b = bs >> 3, s = bs & 7;
    const int t = threadIdx.x;
    const int w = t * 4;
    const long gbase = (long)b * 12288 + s * 1536;
    const long hbase = (long)b * 4096 + s * 512;

    f32x4 rz_r = *(const f32x4*)(gi + gbase + w);            // ir+hr
    f32x4 rz_z = *(const f32x4*)(gi + gbase + 512 + w);      // iz+hz
    f32x4 in_  = *(const f32x4*)(gi + gbase + 1024 + w);     // inn
    f32x4 hn   = *(const f32x4*)(hn_buf + hbase + w);        // hn
    f32x4 h    = *(const f32x4*)(hs + hbase + w);

    float gpart = 0.f;
    f32x4 hnew;
    u16 hb[4], pb[4];
#pragma unroll
    for (int i = 0; i < 4; i++) {
        float r  = sigmoidf_(rz_r[i]);
        float zz = sigmoidf_(rz_z[i]);
        float n  = tanhf(in_[i] + r * hn[i]);
        float hv = (1.f - zz) * n + zz * h[i];
        hnew[i] = hv;
        hb[i] = f2bf(hv);
        gpart += bf2f(Wg[s * 512 + w + i]) * hv;
        float ph = bf2f(phase[s * 512 + w + i]);
        float pg = bf2f(pgain[s * 512 + w + i]);
        float gain = (pg > 20.f) ? pg : log1pf(expf(pg));   // softplus
        float c = cosf(hv + ph);
        pb[i] = f2bf(c * c * gain);
    }
    *(f32x4*)(hs + hbase + w) = hnew;
    *(ushort4*)(hs_b + hbase + w)  = make_ushort4(hb[0], hb[1], hb[2], hb[3]);
    *(ushort4*)(prism + hbase + w) = make_ushort4(pb[0], pb[1], pb[2], pb[3]);

    // block-reduce gate dot (512 elems)
#pragma unroll
    for (int off = 32; off; off >>= 1) gpart += __shfl_down(gpart, off, 64);
    __shared__ float red[2];
    if ((t & 63) == 0) red[t >> 6] = gpart;
    __syncthreads();
    if (t == 0) gate[bs] = sigmoidf_(red[0] + red[1] + bf2f(bg[s]));
}

// ---------------------------------------------------------------------------
// delta = sum_s upd / sqrt(S);  h = tanh(h*decay + delta); shared[:,0:512] = h
// ---------------------------------------------------------------------------
__global__ __launch_bounds__(256) void hupd_k(const float* __restrict__ upd,
                                              float* __restrict__ h,
                                              u16* __restrict__ shared_b,
                                              const u16* __restrict__ decay_p) {
    const int idx = blockIdx.x * 256 + threadIdx.x;   // over B*W
    const int b = idx >> 9, w = idx & 511;
    const long base = (long)b * 4096 + w;
    float dsum = 0.f;
#pragma unroll
    for (int s = 0; s < 8; s++) dsum += upd[base + s * 512];
    const float decay = sigmoidf_(bf2f(decay_p[0]));
    const float hv = tanhf(h[idx] * decay + dsum * 0.35355339059327373f);
    h[idx] = hv;
    shared_b[(long)b * 1024 + w] = f2bf(hv);
}

// ---------------------------------------------------------------------------
// Final head: out[b,j] = h[b,:] . W_out[j,:] + b_out[j]   (one wave per b)
// Output dtype follows detected input dtype (bf16 vs f32).
// ---------------------------------------------------------------------------
__global__ __launch_bounds__(64) void out_k(const float* __restrict__ h,
                                            const u16* __restrict__ Wout,
                                            const u16* __restrict__ bout,
                                            void* __restrict__ out,
                                            const int* __restrict__ flag) {
    const int b = blockIdx.x, lane = threadIdx.x;
    const int isbf = *flag;
    for (int j = 0; j < 10; j++) {
        float p = 0.f;
#pragma unroll
        for (int k = 0; k < 8; k++) {
            int w = lane + k * 64;
            p += h[(long)b * 512 + w] * bf2f(Wout[j * 512 + w]);
        }
#pragma unroll
        for (int off = 32; off; off >>= 1) p += __shfl_down(p, off, 64);
        if (lane == 0) {
            float val = p + bf2f(bout[j]);
            if (isbf) ((u16*)out)[b * 10 + j] = f2bf(val);
            else      ((float*)out)[b * 10 + j] = val;
        }
    }
}

// ---------------------------------------------------------------------------
extern "C" void kernel_launch(void* const* d_in, const int* in_sizes, int n_in,
                              void* d_out, int out_size, void* d_ws, size_t ws_size,
                              hipStream_t stream) {
    (void)n_in; (void)out_size; (void)ws_size;
    const int* x = (const int*)d_in[0];

    char* pp = (char*)d_ws;
    auto carve = [&](size_t n) { char* r = pp; pp += (n + 255) & ~(size_t)255; return (void*)r; };

    // --- canonical bf16 parameter block (~44 MB) ---
    CT ct;
    size_t ctot = 0;
    for (int i = 0; i < 20; i++) {
        ct.src[i] = d_in[i + 1];
        ct.n[i]   = in_sizes[i + 1];
        ct.off[i] = (int)ctot;
        ctot += ((size_t)in_sizes[i + 1] + 15) & ~(size_t)15;   // 16-elem align
    }
    u16* canon = (u16*)carve(ctot * 2);
    const u16* embed  = canon + ct.off[0];
    const u16* W_mix  = canon + ct.off[1];
    const u16* b_mix  = canon + ct.off[2];
    const u16* W_in   = canon + ct.off[3];
    const u16* b_in   = canon + ct.off[4];
    const u16* W_link = canon + ct.off[5];
    const u16* b_link = canon + ct.off[6];
    const u16* W_ih   = canon + ct.off[7];
    const u16* b_ih   = canon + ct.off[8];
    const u16* W_hh   = canon + ct.off[9];
    const u16* b_hh   = canon + ct.off[10];
    const u16* W_gate = canon + ct.off[11];
    const u16* b_gate = canon + ct.off[12];
    const u16* phase  = canon + ct.off[13];
    const u16* pgain  = canon + ct.off[14];
    const u16* W_delta= canon + ct.off[15];
    const u16* b_delta= canon + ct.off[16];
    const u16* decayp = canon + ct.off[17];
    const u16* W_out  = canon + ct.off[18];
    const u16* b_out  = canon + ct.off[19];

    // --- activations (~119 MB) ---
    int*   flag     = (int*)  carve(256);
    u16*   cat      = (u16*)  carve((size_t)1024 * 1536 * 2);   //  3 MB
    u16*   shared_b = (u16*)  carve((size_t)1024 * 1024 * 2);   //  2 MB
    float* h        = (float*)carve((size_t)1024 * 512 * 4);    //  2 MB
    u16*   f0       = (u16*)  carve((size_t)1024 * 4096 * 2);   //  8 MB
    u16*   feats    = (u16*)  carve((size_t)1024 * 4096 * 2);   //  8 MB
    float* hs       = (float*)carve((size_t)1024 * 4096 * 4);   // 16 MB
    u16*   hs_b     = (u16*)  carve((size_t)1024 * 4096 * 2);   //  8 MB
    float* gi       = (float*)carve((size_t)1024 * 12288 * 4);  // 48 MB
    float* hn       = (float*)carve((size_t)1024 * 4096 * 4);   // 16 MB (upd aliases)
    u16*   prism    = (u16*)  carve((size_t)1024 * 4096 * 2);   //  8 MB
    float* gate     = (float*)carve((size_t)1024 * 8 * 4);      // 32 KB
    float* upd      = hn;  // dead after gru_k reads hn

    (void)hipMemsetAsync(hs,   0, (size_t)1024 * 4096 * 4, stream);
    (void)hipMemsetAsync(hs_b, 0, (size_t)1024 * 4096 * 2, stream);

    detect_k<<<dim3(1), dim3(256), 0, stream>>>((const u16*)d_in[1], flag);
    conv_k<<<dim3(1024), dim3(256), 0, stream>>>(ct, canon, flag);

    encode_k<<<dim3(1024), dim3(256), 0, stream>>>(x, embed, cat);

    {   // summary = tanh(cat @ W_mix^T + b_mix) ; h0 = summary; shared = [h0, summary]
        GP p{}; p.A = cat; p.lda = 1536; p.Bw = W_mix; p.bOff = 0; p.K = 1536;
        p.bias = b_mix; p.biasOff = 0; p.C = shared_b; p.ldc = 1024; p.cOff = 0; p.C2 = h;
        gemm_k<4><<<dim3(8, 4, 1), dim3(256), 0, stream>>>(p);
    }

    for (int step = 0; step < 12; ++step) {
        {   // f0 = tanh(shared @ W_in^T + b_in)   [B, S*W]
            GP p{}; p.A = shared_b; p.lda = 1024; p.Bw = W_in; p.bOff = 0; p.K = 1024;
            p.bias = b_in; p.biasOff = 0; p.C = f0; p.ldc = 4096; p.cOff = 0;
            gemm_k<0><<<dim3(8, 32, 1), dim3(256), 0, stream>>>(p);
        }
        {   // feats = tanh(f0 + prev @ W_link^T + b_link), prev = pocket (s-1)%8
            GP p{}; p.A = f0; p.lda = 4096;
            for (int s = 0; s < 8; s++) p.aOff[s] = (long)((s + 7) & 7) * 512;
            p.Bw = W_link; p.bOff = (long)512 * 512; p.K = 512;
            p.bias = b_link; p.biasOff = 512;
            p.add = f0; p.ldadd = 4096; p.addOff = 512;
            p.C = feats; p.ldc = 4096; p.cOff = 512;
            gemm_k<1><<<dim3(8, 4, 8), dim3(256), 0, stream>>>(p);
        }
        {   // gi = feats @ W_ih^T + b_ih
            GP p{}; p.A = feats; p.lda = 4096;
            for (int s = 0; s < 8; s++) p.aOff[s] = (long)s * 512;
            p.Bw = W_ih; p.bOff = (long)1536 * 512; p.K = 512;
            p.bias = b_ih; p.biasOff = 1536;
            p.C = gi; p.ldc = 12288; p.cOff = 1536;
            gemm_k<2><<<dim3(8, 12, 8), dim3(256), 0, stream>>>(p);
        }
        {   // gh = hs @ W_hh^T + b_hh ; r/z parts += into gi, n part -> hn
            GP p{}; p.A = hs_b; p.lda = 4096;
            for (int s = 0; s < 8; s++) p.aOff[s] = (long)s * 512;
            p.Bw = W_hh; p.bOff = (long)1536 * 512; p.K = 512;
            p.bias = b_hh; p.biasOff = 1536;
            p.C = gi; p.ldc = 12288; p.cOff = 1536; p.C2 = hn;
            gemm_k<5><<<dim3(8, 12, 8), dim3(256), 0, stream>>>(p);
        }
        gru_k<<<dim3(8192), dim3(128), 0, stream>>>(gi, hn, hs, hs_b, prism, gate,
                                                    W_gate, b_gate, phase, pgain);
        {   // upd = gate * tanh(prism @ W_delta^T + b_delta)   (upd aliases hn)
            GP p{}; p.A = prism; p.lda = 4096;
            for (int s = 0; s < 8; s++) p.aOff[s] = (long)s * 512;
            p.Bw = W_delta; p.bOff = (long)512 * 512; p.K = 512;
            p.bias = b_delta; p.biasOff = 512; p.gate = gate;
            p.C = upd; p.ldc = 4096; p.cOff = 512;
            gemm_k<3><<<dim3(8, 4, 8), dim3(256), 0, stream>>>(p);
        }
        hupd_k<<<dim3(2048), dim3(256), 0, stream>>>(upd, h, shared_b, decayp);
    }

    out_k<<<dim3(1024), dim3(64), 0, stream>>>(h, W_out, b_out, d_out, flag);
}